// Round 6
// baseline (53.588 us; speedup 1.0000x reference)
//
#include <hip/hip_runtime.h>
#include <cmath>

// Problem constants
#define SS 2048
#define BB 32
#define HH 1024

// ---------------------------------------------------------------------------
// K1a: partial u[h] = sum over a 64-wide k-chunk of v[k] * We[k][h]
//      We[k][h] = attn_W[k][HH + h], attn_W row-major (HH, 2*HH)
// grid (4, 16), block 256  -> 64 blocks, each reads 64KB (latency-hidden)
// [PROVEN round-1/5 binary: DO NOT TOUCH — round-4 reshape cost +13us]
// ---------------------------------------------------------------------------
__global__ __launch_bounds__(256) void partial_u_kernel(
    const float* __restrict__ W, const float* __restrict__ v,
    float* __restrict__ partial) {
  int h  = blockIdx.x * 256 + threadIdx.x;  // 0..1023
  int k0 = blockIdx.y * 64;
  float acc = 0.f;
#pragma unroll 8
  for (int k = k0; k < k0 + 64; ++k)
    acc += v[k] * W[(size_t)k * (2 * HH) + HH + h];
  partial[blockIdx.y * HH + h] = acc;
}

// K1b: u[h] = sum of 16 partials (deterministic, no atomics)
__global__ __launch_bounds__(256) void reduce_u_kernel(
    const float* __restrict__ partial, float* __restrict__ u) {
  int h = blockIdx.x * 256 + threadIdx.x;
  float acc = 0.f;
#pragma unroll
  for (int c = 0; c < 16; ++c) acc += partial[c * HH + h];
  u[h] = acc;
}

// ---------------------------------------------------------------------------
// K2: energy[b*S + s] = dot(enc[s,b,:], u)
// ROUND-6 CHANGE (single variable): same grid (2048 blocks, 32 waves/CU),
// but each wave grid-strides over 8 rows with a 2-deep load pipeline and
// u register-cached once per wave. Keeps the memory pipe fed across the
// shuffle/store tail instead of retiring the wave after one row.
// ---------------------------------------------------------------------------
#define NWAVES 8192  // 2048 blocks * 4 waves
__global__ __launch_bounds__(256) void energy_kernel(
    const float* __restrict__ enc, const float* __restrict__ u,
    float* __restrict__ energy) {
  int wave = blockIdx.x * 4 + (threadIdx.x >> 6);  // 0..8191
  int lane = threadIdx.x & 63;

  const float4* u4 = reinterpret_cast<const float4*>(u);
  float4 uv[4];
#pragma unroll
  for (int j = 0; j < 4; ++j) uv[j] = u4[lane + j * 64];

  const float4* base = reinterpret_cast<const float4*>(enc);

  // prologue: load first row
  float4 cur[4];
  {
    const float4* e4 = base + (size_t)wave * (HH / 4);
#pragma unroll
    for (int j = 0; j < 4; ++j) cur[j] = e4[lane + j * 64];
  }

#pragma unroll
  for (int it = 0; it < 8; ++it) {
    int row = wave + it * NWAVES;
    // issue next row's loads before consuming current
    float4 nxt[4];
    if (it < 7) {
      const float4* e4 = base + (size_t)(row + NWAVES) * (HH / 4);
#pragma unroll
      for (int j = 0; j < 4; ++j) nxt[j] = e4[lane + j * 64];
    }
    float acc = 0.f;
#pragma unroll
    for (int j = 0; j < 4; ++j)
      acc += cur[j].x * uv[j].x + cur[j].y * uv[j].y +
             cur[j].z * uv[j].z + cur[j].w * uv[j].w;
#pragma unroll
    for (int m = 32; m; m >>= 1) acc += __shfl_xor(acc, m, 64);
    if (lane == 0) {
      int s_ = row / BB;
      int b_ = row % BB;
      energy[(size_t)b_ * SS + s_] = acc;
    }
#pragma unroll
    for (int j = 0; j < 4; ++j) cur[j] = nxt[j];
  }
}

// ---------------------------------------------------------------------------
// K3: in-place row softmax on d_out: 32 rows of 2048. One block per row.
// ---------------------------------------------------------------------------
__global__ __launch_bounds__(256) void softmax_kernel(float* __restrict__ e) {
  int b = blockIdx.x;
  float* row = e + (size_t)b * SS;
  int tid  = threadIdx.x;
  int lane = tid & 63;
  int wv   = tid >> 6;

  float vals[8];
  float mx = -INFINITY;
#pragma unroll
  for (int i = 0; i < 8; ++i) {
    vals[i] = row[tid + i * 256];
    mx = fmaxf(mx, vals[i]);
  }
#pragma unroll
  for (int m = 32; m; m >>= 1) mx = fmaxf(mx, __shfl_xor(mx, m, 64));

  __shared__ float red_max[4];
  __shared__ float red_sum[4];
  if (lane == 0) red_max[wv] = mx;
  __syncthreads();
  mx = fmaxf(fmaxf(red_max[0], red_max[1]), fmaxf(red_max[2], red_max[3]));

  float sum = 0.f;
#pragma unroll
  for (int i = 0; i < 8; ++i) {
    vals[i] = expf(vals[i] - mx);
    sum += vals[i];
  }
#pragma unroll
  for (int m = 32; m; m >>= 1) sum += __shfl_xor(sum, m, 64);
  if (lane == 0) red_sum[wv] = sum;
  __syncthreads();
  sum = red_sum[0] + red_sum[1] + red_sum[2] + red_sum[3];

  float inv = 1.0f / sum;
#pragma unroll
  for (int i = 0; i < 8; ++i) row[tid + i * 256] = vals[i] * inv;
}

extern "C" void kernel_launch(void* const* d_in, const int* in_sizes, int n_in,
                              void* d_out, int out_size, void* d_ws, size_t ws_size,
                              hipStream_t stream) {
  const float* enc = (const float*)d_in[0];   // (S,B,H)
  // d_in[1] rnn_hidden, d_in[3] attn_b: cancel under softmax (shift-invariant)
  const float* W = (const float*)d_in[2];     // (H, 2H)
  const float* v = (const float*)d_in[4];     // (1, H)
  float* out = (float*)d_out;                 // (B,1,S) = B*S floats

  float* u       = (float*)d_ws;              // 4 KB
  float* partial = (float*)d_ws + HH;         // 64 KB

  partial_u_kernel<<<dim3(4, 16), 256, 0, stream>>>(W, v, partial);
  reduce_u_kernel<<<4, 256, 0, stream>>>(partial, u);
  energy_kernel<<<(SS * BB) / 4 / 8, 256, 0, stream>>>(enc, u, out);
  softmax_kernel<<<BB, 256, 0, stream>>>(out);
}